// Round 1
// baseline (113.137 us; speedup 1.0000x reference)
//
#include <hip/hip_runtime.h>
#include <math.h>

#define N_QUBITS 10
#define N_LAYERS 2
#define BATCH 4096
#define REGS 16   // amplitudes per lane: 1024 / 64

// amp flat index = lane*16 + r ; bits 9..4 = lane bits, bits 3..0 = reg bits
// wire w  <->  bit b = 9 - w

__device__ __forceinline__ float shfx(float v, int mask) {
    return __shfl_xor(v, mask, 64);
}

// RY (real matrix [[c,-s],[s,c]]) on bit b
__device__ __forceinline__ void apply_ry(float* ar, float* ai, int b,
                                         float c, float s, int lane) {
    if (b < 4) {
        int m = 1 << b;
        #pragma unroll
        for (int r = 0; r < REGS; ++r) {
            if (!(r & m)) {
                int r1 = r | m;
                float a0r = ar[r],  a0i = ai[r];
                float a1r = ar[r1], a1i = ai[r1];
                ar[r]  = c * a0r - s * a1r;  ai[r]  = c * a0i - s * a1i;
                ar[r1] = s * a0r + c * a1r;  ai[r1] = s * a0i + c * a1i;
            }
        }
    } else {
        int lm = 1 << (b - 4);
        bool hi = (lane & lm) != 0;
        float ss = hi ? s : -s;      // lo: c*own - s*partner ; hi: c*own + s*partner
        #pragma unroll
        for (int r = 0; r < REGS; ++r) {
            float pr = shfx(ar[r], lm);
            float pi = shfx(ai[r], lm);
            ar[r] = c * ar[r] + ss * pr;
            ai[r] = c * ai[r] + ss * pi;
        }
    }
}

// general complex 2x2 gate on bit b
__device__ __forceinline__ void apply_u(float* ar, float* ai, int b,
                                        float u00r, float u00i, float u01r, float u01i,
                                        float u10r, float u10i, float u11r, float u11i,
                                        int lane) {
    if (b < 4) {
        int m = 1 << b;
        #pragma unroll
        for (int r = 0; r < REGS; ++r) {
            if (!(r & m)) {
                int r1 = r | m;
                float a0r = ar[r],  a0i = ai[r];
                float a1r = ar[r1], a1i = ai[r1];
                ar[r]  = u00r*a0r - u00i*a0i + u01r*a1r - u01i*a1i;
                ai[r]  = u00r*a0i + u00i*a0r + u01r*a1i + u01i*a1r;
                ar[r1] = u10r*a0r - u10i*a0i + u11r*a1r - u11i*a1i;
                ai[r1] = u10r*a0i + u10i*a0r + u11r*a1i + u11i*a1r;
            }
        }
    } else {
        int lm = 1 << (b - 4);
        bool hi = (lane & lm) != 0;
        float uor = hi ? u11r : u00r, uoi = hi ? u11i : u00i;  // coeff of own amp
        float upr = hi ? u10r : u01r, upi = hi ? u10i : u01i;  // coeff of partner amp
        #pragma unroll
        for (int r = 0; r < REGS; ++r) {
            float pr = shfx(ar[r], lm);
            float pi = shfx(ai[r], lm);
            float nr = uor*ar[r] - uoi*ai[r] + upr*pr - upi*pi;
            float ni = uor*ai[r] + uoi*ar[r] + upr*pi + upi*pr;
            ar[r] = nr; ai[r] = ni;
        }
    }
}

// CNOT: control bit bc, target bit bt (flat-index bit positions)
__device__ __forceinline__ void apply_cnot(float* ar, float* ai, int bc, int bt, int lane) {
    if (bc < 4 && bt < 4) {                 // both in-register: pure reg permutation
        int mc = 1 << bc, mt = 1 << bt;
        #pragma unroll
        for (int r = 0; r < REGS; ++r) {
            if ((r & mc) && !(r & mt)) {
                int r1 = r | mt;
                float tr = ar[r], ti = ai[r];
                ar[r] = ar[r1]; ai[r] = ai[r1];
                ar[r1] = tr;    ai[r1] = ti;
            }
        }
    } else if (bc >= 4 && bt < 4) {         // control in lane bits: conditional reg swap
        int lm = 1 << (bc - 4), mt = 1 << bt;
        bool ctrl = (lane & lm) != 0;
        #pragma unroll
        for (int r = 0; r < REGS; ++r) {
            if (!(r & mt)) {
                int r1 = r | mt;
                float t0r = ar[r],  t0i = ai[r];
                float t1r = ar[r1], t1i = ai[r1];
                ar[r]  = ctrl ? t1r : t0r;  ai[r]  = ctrl ? t1i : t0i;
                ar[r1] = ctrl ? t0r : t1r;  ai[r1] = ctrl ? t0i : t1i;
            }
        }
    } else if (bc < 4 && bt >= 4) {         // target in lane bits: shfl the bc=1 regs
        int mc = 1 << bc, lm = 1 << (bt - 4);
        #pragma unroll
        for (int r = 0; r < REGS; ++r) {
            if (r & mc) {
                ar[r] = shfx(ar[r], lm);
                ai[r] = shfx(ai[r], lm);
            }
        }
    } else {                                // both in lane bits: conditional lane swap
        int lmc = 1 << (bc - 4), lmt = 1 << (bt - 4);
        bool ctrl = (lane & lmc) != 0;
        #pragma unroll
        for (int r = 0; r < REGS; ++r) {
            float pr = shfx(ar[r], lmt);
            float pi = shfx(ai[r], lmt);
            ar[r] = ctrl ? pr : ar[r];
            ai[r] = ctrl ? pi : ai[r];
        }
    }
}

// Precompute the 20 batch-uniform Rot matrices into workspace.
// Layout: rotmat[(l*10+w)*8] = {u00r,u00i,u01r,u01i,u10r,u10i,u11r,u11i}
__global__ void rot_precompute(const float* __restrict__ weights, float* __restrict__ rotmat) {
    int i = threadIdx.x;
    if (i >= N_LAYERS * N_QUBITS) return;
    float phi = weights[i * 3 + 0];
    float th  = weights[i * 3 + 1];
    float om  = weights[i * 3 + 2];
    float c, s;  sincosf(0.5f * th, &s, &c);
    float sa, ca; sincosf(0.5f * (phi + om), &sa, &ca);  // ep = ca - i*sa
    float sb, cb; sincosf(0.5f * (phi - om), &sb, &cb);  // em = cb + i*sb
    float* u = rotmat + i * 8;
    u[0] =  c * ca;  u[1] = -c * sa;   // u00 = ep*c
    u[2] = -s * cb;  u[3] = -s * sb;   // u01 = -em*s
    u[4] =  s * cb;  u[5] = -s * sb;   // u10 = conj(em)*s
    u[6] =  c * ca;  u[7] =  c * sa;   // u11 = conj(ep)*c
}

__global__ __launch_bounds__(256) void qnn_kernel(
    const float* __restrict__ x, const float* __restrict__ rotmat,
    const float* __restrict__ w1, const float* __restrict__ b1,
    const float* __restrict__ w2, const float* __restrict__ b2,
    float* __restrict__ out)
{
    int tid  = blockIdx.x * blockDim.x + threadIdx.x;
    int wave = tid >> 6;          // sample index
    int lane = tid & 63;
    if (wave >= BATCH) return;

    // Per-sample RY angles: lane w (<10) computes sincos(x/2), broadcast at use.
    float myc = 1.0f, mys = 0.0f;
    if (lane < N_QUBITS) {
        float th = 0.5f * x[wave * N_QUBITS + lane];
        sincosf(th, &mys, &myc);
    }

    // |0...0>
    float ar[REGS], ai[REGS];
    #pragma unroll
    for (int r = 0; r < REGS; ++r) { ar[r] = 0.0f; ai[r] = 0.0f; }
    if (lane == 0) ar[0] = 1.0f;

    // AngleEmbedding: RY(x_w) on wire w  (bit 9-w)
    #pragma unroll
    for (int w = 0; w < N_QUBITS; ++w) {
        float c = __shfl(myc, w, 64);
        float s = __shfl(mys, w, 64);
        apply_ry(ar, ai, 9 - w, c, s, lane);
    }

    // StronglyEntanglingLayers
    #pragma unroll
    for (int l = 0; l < N_LAYERS; ++l) {
        #pragma unroll
        for (int w = 0; w < N_QUBITS; ++w) {
            const float* u = rotmat + (l * N_QUBITS + w) * 8;
            apply_u(ar, ai, 9 - w,
                    u[0], u[1], u[2], u[3], u[4], u[5], u[6], u[7], lane);
        }
        int rng = (l % (N_QUBITS - 1)) + 1;
        #pragma unroll
        for (int w = 0; w < N_QUBITS; ++w) {
            int t = (w + rng) % N_QUBITS;
            apply_cnot(ar, ai, 9 - w, 9 - t, lane);
        }
    }

    // <Z_w> accumulation
    float z[N_QUBITS];
    #pragma unroll
    for (int w = 0; w < N_QUBITS; ++w) z[w] = 0.0f;
    #pragma unroll
    for (int r = 0; r < REGS; ++r) {
        int idx = (lane << 4) | r;
        float p = ar[r] * ar[r] + ai[r] * ai[r];
        #pragma unroll
        for (int w = 0; w < N_QUBITS; ++w) {
            z[w] += ((idx >> (9 - w)) & 1) ? -p : p;
        }
    }
    // butterfly reduce across the wave
    #pragma unroll
    for (int off = 32; off >= 1; off >>= 1) {
        #pragma unroll
        for (int w = 0; w < N_QUBITS; ++w)
            z[w] += __shfl_xor(z[w], off, 64);
    }

    // tiny MLP on lane 0: 10 -> 8 (relu) -> 1 (sigmoid)
    if (lane == 0) {
        float acc2 = b2[0];
        #pragma unroll
        for (int j = 0; j < 8; ++j) {
            float h = b1[j];
            #pragma unroll
            for (int w = 0; w < N_QUBITS; ++w)
                h = fmaf(z[w], w1[j * N_QUBITS + w], h);
            h = fmaxf(h, 0.0f);
            acc2 = fmaf(h, w2[j], acc2);
        }
        out[wave] = 1.0f / (1.0f + expf(-acc2));
    }
}

extern "C" void kernel_launch(void* const* d_in, const int* in_sizes, int n_in,
                              void* d_out, int out_size, void* d_ws, size_t ws_size,
                              hipStream_t stream) {
    const float* x       = (const float*)d_in[0];
    const float* weights = (const float*)d_in[1];
    const float* w1      = (const float*)d_in[2];
    const float* b1      = (const float*)d_in[3];
    const float* w2      = (const float*)d_in[4];
    const float* b2      = (const float*)d_in[5];
    float* out = (float*)d_out;
    float* rotmat = (float*)d_ws;   // 160 floats

    rot_precompute<<<1, 32, 0, stream>>>(weights, rotmat);

    int threads = 256;                       // 4 samples per block
    int blocks  = (BATCH * 64) / threads;    // 1024
    qnn_kernel<<<blocks, threads, 0, stream>>>(x, rotmat, w1, b1, w2, b2, out);
}

// Round 2
// 80.138 us; speedup vs baseline: 1.4118x; 1.4118x over previous
//
#include <hip/hip_runtime.h>
#include <math.h>

#define NQ 10
#define BATCH 4096
#define REGS 16
#define T_OFF 128   // float offset of diagonal table in ws

struct cplx { float r, i; };
__device__ __forceinline__ cplx cmul(cplx a, cplx b) {
    return { fmaf(a.r, b.r, -(a.i * b.i)), fmaf(a.r, b.i, a.i * b.r) };
}
__device__ __forceinline__ cplx csel(bool hi, cplx b, cplx a) { return hi ? b : a; }
__device__ __forceinline__ float shfx(float v, int m) { return __shfl_xor(v, m, 64); }

// ------------------------------------------------------------------
// Precompute (batch-uniform):
//  ws[0..79]  : per wire w: {c0,s0, cos(phi0/2),sin(phi0/2), cos(om0/2),sin(om0/2), c1,s1}
//  ws[T_OFF..]: T[j] = exp(i * sum_w (bit_{9-w}(j) ? +1 : -1) * phi1_w/2), 1024 cplx
// (layer-1 RZ(omega) dropped: diagonal before a basis permutation + |.|^2)
// ------------------------------------------------------------------
__global__ void precompute(const float* __restrict__ weights, float* __restrict__ ws) {
    int j = blockIdx.x * blockDim.x + threadIdx.x;   // 0..1023
    if (j < NQ) {
        float phi0 = weights[j * 3 + 0];
        float th0  = weights[j * 3 + 1];
        float om0  = weights[j * 3 + 2];
        float th1  = weights[(NQ + j) * 3 + 1];
        float c0, s0, cp, sp, co, so, c1, s1;
        sincosf(0.5f * th0,  &s0, &c0);
        sincosf(0.5f * phi0, &sp, &cp);
        sincosf(0.5f * om0,  &so, &co);
        sincosf(0.5f * th1,  &s1, &c1);
        float* p = ws + j * 8;
        p[0] = c0; p[1] = s0; p[2] = cp; p[3] = sp;
        p[4] = co; p[5] = so; p[6] = c1; p[7] = s1;
    }
    float phase = 0.f;
    #pragma unroll
    for (int w = 0; w < NQ; ++w) {
        float h = 0.5f * weights[(NQ + w) * 3 + 0];
        phase += ((j >> (9 - w)) & 1) ? h : -h;
    }
    float ti, tr;
    sincosf(phase, &ti, &tr);
    ws[T_OFF + 2 * j]     = tr;
    ws[T_OFF + 2 * j + 1] = ti;
}

// real RY on flat bit b (amp index j = lane*16 + r; bits 9..4 lane, 3..0 reg)
__device__ __forceinline__ void apply_ry(float* ar, float* ai, int b,
                                         float c, float s, int lane) {
    if (b < 4) {
        int m = 1 << b;
        #pragma unroll
        for (int r = 0; r < REGS; ++r) {
            if (!(r & m)) {
                int r1 = r | m;
                float a0r = ar[r],  a0i = ai[r];
                float a1r = ar[r1], a1i = ai[r1];
                ar[r]  = c * a0r - s * a1r;  ai[r]  = c * a0i - s * a1i;
                ar[r1] = s * a0r + c * a1r;  ai[r1] = s * a0i + c * a1i;
            }
        }
    } else {
        int lm = 1 << (b - 4);
        float ss = ((lane >> (b - 4)) & 1) ? s : -s;
        #pragma unroll
        for (int r = 0; r < REGS; ++r) {
            float pr = shfx(ar[r], lm);
            float pi = shfx(ai[r], lm);
            ar[r] = fmaf(ss, pr, c * ar[r]);
            ai[r] = fmaf(ss, pi, c * ai[r]);
        }
    }
}

__global__ __launch_bounds__(256) void qnn_kernel(
    const float* __restrict__ x, const float* __restrict__ ws,
    const float* __restrict__ w1, const float* __restrict__ b1,
    const float* __restrict__ w2, const float* __restrict__ b2,
    float* __restrict__ out)
{
    int tid  = blockIdx.x * blockDim.x + threadIdx.x;
    int wave = tid >> 6;
    int lane = tid & 63;

    // ---- lanes 0..9: fused column (Rot0 * RY(x)) |0> = (alpha, beta) ----
    float Ar = 0.f, Ai = 0.f, Br = 0.f, Bi = 0.f;
    if (lane < NQ) {
        float xv = x[wave * NQ + lane];
        float sx, cx;
        sincosf(0.5f * xv, &sx, &cx);
        const float* p = ws + lane * 8;
        float c0 = p[0], s0 = p[1], cp = p[2], sp = p[3], co = p[4], so = p[5];
        // u0 = e^{-i phi/2} * cx ; u1 = e^{+i phi/2} * sx
        float u0r = cp * cx, u0i = -sp * cx;
        float u1r = cp * sx, u1i =  sp * sx;
        float ar_ = c0 * u0r - s0 * u1r, ai_ = c0 * u0i - s0 * u1i;
        float br_ = s0 * u0r + c0 * u1r, bi_ = s0 * u0i + c0 * u1i;
        Ar = ar_ * co + ai_ * so;  Ai = ai_ * co - ar_ * so;   // * e^{-i om/2}
        Br = br_ * co - bi_ * so;  Bi = bi_ * co + br_ * so;   // * e^{+i om/2}
    }

    // ---- broadcast per-wire (alpha,beta); fold into product tree ----
    // Ring-0 permutation Q(j):  wire-w factor selected by parity(j & M_w):
    //  w0:0x201 w1:0x301 w2:0x180 w3:0x0C0 w4:0x060 w5:0x030
    //  w6:0x018 w7:0x00C w8:0x006 w9:0x003
    cplx a0w{__shfl(Ar,0,64),__shfl(Ai,0,64)}, b0w{__shfl(Br,0,64),__shfl(Bi,0,64)};
    cplx a1w{__shfl(Ar,1,64),__shfl(Ai,1,64)}, b1w{__shfl(Br,1,64),__shfl(Bi,1,64)};
    cplx a2w{__shfl(Ar,2,64),__shfl(Ai,2,64)}, b2w{__shfl(Br,2,64),__shfl(Bi,2,64)};
    cplx a3w{__shfl(Ar,3,64),__shfl(Ai,3,64)}, b3w{__shfl(Br,3,64),__shfl(Bi,3,64)};
    cplx a4w{__shfl(Ar,4,64),__shfl(Ai,4,64)}, b4w{__shfl(Br,4,64),__shfl(Bi,4,64)};
    cplx a5w{__shfl(Ar,5,64),__shfl(Ai,5,64)}, b5w{__shfl(Br,5,64),__shfl(Bi,5,64)};
    cplx a6w{__shfl(Ar,6,64),__shfl(Ai,6,64)}, b6w{__shfl(Br,6,64),__shfl(Bi,6,64)};
    cplx a7w{__shfl(Ar,7,64),__shfl(Ai,7,64)}, b7w{__shfl(Br,7,64),__shfl(Bi,7,64)};
    cplx a8w{__shfl(Ar,8,64),__shfl(Ai,8,64)}, b8w{__shfl(Br,8,64),__shfl(Bi,8,64)};
    cplx a9w{__shfl(Ar,9,64),__shfl(Ai,9,64)}, b9w{__shfl(Br,9,64),__shfl(Bi,9,64)};

    // lane-only selections (w2..w5): masks on lane bits {0x18,0x0C,0x06,0x03}
    bool L2 = __popc(lane & 0x18) & 1;
    bool L3 = __popc(lane & 0x0C) & 1;
    bool L4 = __popc(lane & 0x06) & 1;
    bool L5 = __popc(lane & 0x03) & 1;
    cplx lp = csel(L2, b2w, a2w);
    lp = cmul(lp, csel(L3, b3w, a3w));
    lp = cmul(lp, csel(L4, b4w, a4w));
    lp = cmul(lp, csel(L5, b5w, a5w));

    // w0: lane bit5 ^ r0 ; w1: parity(lane&0x30) ^ r0
    bool Lb5 = (lane >> 5) & 1;
    bool L45 = __popc(lane & 0x30) & 1;
    cplx A0 = cmul(csel(Lb5, b0w, a0w), csel(L45, b1w, a1w));
    cplx A1 = cmul(csel(!Lb5, b0w, a0w), csel(!L45, b1w, a1w));

    // w6: lane bit0 ^ r3
    bool Lb0 = lane & 1;
    cplx B0 = csel(Lb0, b6w, a6w);
    cplx B1 = csel(!Lb0, b6w, a6w);

    // w7..w9: compile-time reg parities (r2^r3, r1^r2, r0^r1)
    cplx g00 = cmul(a8w, a9w), g01 = cmul(a8w, b9w);
    cplx g10 = cmul(b8w, a9w), g11 = cmul(b8w, b9w);
    cplx C[2][2][2];
    C[0][0][0] = cmul(a7w, g00); C[0][0][1] = cmul(a7w, g01);
    C[0][1][0] = cmul(a7w, g10); C[0][1][1] = cmul(a7w, g11);
    C[1][0][0] = cmul(b7w, g00); C[1][0][1] = cmul(b7w, g01);
    C[1][1][0] = cmul(b7w, g10); C[1][1][1] = cmul(b7w, g11);

    cplx LA0 = cmul(lp, A0), LA1 = cmul(lp, A1);
    cplx LAB[2][2];                       // [r0][r3]
    LAB[0][0] = cmul(LA0, B0); LAB[0][1] = cmul(LA0, B1);
    LAB[1][0] = cmul(LA1, B0); LAB[1][1] = cmul(LA1, B1);

    // ---- build amps (state after embed+Rot0+ring0), multiply diag table T ----
    float ar[REGS], ai[REGS];
    const float4* Tp = (const float4*)(ws + T_OFF + lane * 32);  // 16 cplx per lane
    #pragma unroll
    for (int k = 0; k < 8; ++k) {
        float4 q = Tp[k];
        #pragma unroll
        for (int h = 0; h < 2; ++h) {
            int r = 2 * k + h;
            int p7 = ((r >> 2) ^ (r >> 3)) & 1;
            int p8 = ((r >> 1) ^ (r >> 2)) & 1;
            int p9 = (r ^ (r >> 1)) & 1;
            cplx v = cmul(LAB[r & 1][(r >> 3) & 1], C[p7][p8][p9]);
            cplx t = h ? cplx{q.z, q.w} : cplx{q.x, q.y};
            v = cmul(v, t);
            ar[r] = v.r; ai[r] = v.i;
        }
    }

    // ---- layer-1: real RY(theta1_w) on each wire (RZ phases already in T) ----
    #pragma unroll
    for (int v = 0; v < NQ; ++v) {
        float c1 = ws[v * 8 + 6];
        float s1 = ws[v * 8 + 7];
        apply_ry(ar, ai, 9 - v, c1, s1, lane);
    }

    // ---- measurement: ring-1 CNOTs conjugated into Z-string masks ----
    // Zmask_w: {0x0AA,0x055,0x280,0x140,0x2A0,0x150,0x2A8,0x154,0x2AA,0x155}
    float S0 = 0.f, S4 = 0.f, S5 = 0.f, S8 = 0.f, SA = 0.f;
    #pragma unroll
    for (int r = 0; r < REGS; ++r) {
        float p = fmaf(ar[r], ar[r], ai[r] * ai[r]);
        S0 += p;
        S4 += (__popc(r & 0x4) & 1) ? -p : p;
        S5 += (__popc(r & 0x5) & 1) ? -p : p;
        S8 += (__popc(r & 0x8) & 1) ? -p : p;
        SA += (__popc(r & 0xA) & 1) ? -p : p;
    }
    float z[NQ];
    z[0] = (__popc(lane & 0x0A) & 1) ? -SA : SA;
    z[1] = (__popc(lane & 0x05) & 1) ? -S5 : S5;
    z[2] = (__popc(lane & 0x28) & 1) ? -S0 : S0;
    z[3] = (__popc(lane & 0x14) & 1) ? -S0 : S0;
    z[4] = (__popc(lane & 0x2A) & 1) ? -S0 : S0;
    z[5] = (__popc(lane & 0x15) & 1) ? -S0 : S0;
    z[6] = (__popc(lane & 0x2A) & 1) ? -S8 : S8;
    z[7] = (__popc(lane & 0x15) & 1) ? -S4 : S4;
    z[8] = (__popc(lane & 0x2A) & 1) ? -SA : SA;
    z[9] = (__popc(lane & 0x15) & 1) ? -S5 : S5;

    #pragma unroll
    for (int off = 32; off >= 1; off >>= 1) {
        #pragma unroll
        for (int w = 0; w < NQ; ++w)
            z[w] += shfx(z[w], off);
    }

    // ---- MLP 10 -> 8 (relu) -> 1 (sigmoid), lane 0 ----
    if (lane == 0) {
        float acc2 = b2[0];
        #pragma unroll
        for (int j = 0; j < 8; ++j) {
            float h = b1[j];
            #pragma unroll
            for (int w = 0; w < NQ; ++w)
                h = fmaf(z[w], w1[j * NQ + w], h);
            h = fmaxf(h, 0.0f);
            acc2 = fmaf(h, w2[j], acc2);
        }
        out[wave] = 1.0f / (1.0f + expf(-acc2));
    }
}

extern "C" void kernel_launch(void* const* d_in, const int* in_sizes, int n_in,
                              void* d_out, int out_size, void* d_ws, size_t ws_size,
                              hipStream_t stream) {
    const float* x       = (const float*)d_in[0];
    const float* weights = (const float*)d_in[1];
    const float* w1      = (const float*)d_in[2];
    const float* b1      = (const float*)d_in[3];
    const float* w2      = (const float*)d_in[4];
    const float* b2      = (const float*)d_in[5];
    float* out = (float*)d_out;
    float* ws  = (float*)d_ws;   // params (80 f) + T table (2048 f) = 8.5 KB

    precompute<<<4, 256, 0, stream>>>(weights, ws);

    int threads = 256;                      // 4 waves per block
    int blocks  = (BATCH * 64) / threads;   // 1024
    qnn_kernel<<<blocks, threads, 0, stream>>>(x, ws, w1, b1, w2, b2, out);
}

// Round 3
// 74.351 us; speedup vs baseline: 1.5217x; 1.0778x over previous
//
#include <hip/hip_runtime.h>
#include <math.h>

#define NQ 10
#define BATCH 4096

// ============================================================================
// Heisenberg-picture evaluation. Per sample:
//   <Z_w> = <prod| Ring0^+ [ (x)_{b in S_w} M_b ] Ring0 |prod>
// where |prod> = (x)_w (Rot0_w RY(x_w))|0>  (per-wire Bloch vector, sample-dep)
//   M_b = Rot1_b^+ Z Rot1_b = cz Z + cx X + cy Y   (batch-uniform coeffs)
//   S_w = ring-1-conjugated Z-string masks (compile-time, verified vs R2)
// Ring-0 conjugation of each Pauli term is done at COMPILE TIME via template
// recursion over the CNOT chain; sign via symplectic rule.
// Labels: I=0, X=1, Z=2, Y=3  (bit0 = x-part, bit1 = z-part)
// ============================================================================

struct CR { int c, t, flip; };
__host__ __device__ constexpr CR cnot_conj(int lc, int lt) {
    const int xc = lc & 1, zc = (lc >> 1) & 1;
    const int xt = lt & 1, zt = (lt >> 1) & 1;
    const int flip = xc & zt & ((xt ^ zc) ^ 1);
    const int nxt = xt ^ xc;          // x_t ^= x_c
    const int nzc = zc ^ zt;          // z_c ^= z_t
    return { (nzc << 1) | xc, (zt << 1) | nxt, flip };
}

// Process gates H_K=(K,K+1) for K=8..1 (finalizing wire K+1), then H0=(0,1).
// L1 = current label of wire K+1 (carry); L0 = pending label of wire 0.
template<int SM, int K, int L1, int L0, int F>
__device__ __forceinline__ float chain(const float (&B)[NQ][4], const float (&C)[NQ][4], float p) {
    if constexpr (K == 0) {
        constexpr CR r = cnot_conj(L0, L1);     // H0: c=0, t=1
        float v = p;
        if constexpr (r.t != 0) v *= B[1][r.t];
        if constexpr (r.c != 0) v *= B[0][r.c];
        if constexpr (F ^ r.flip) return -v; else return v;
    } else if constexpr ((SM >> K) & 1) {
        float s = 0.f;
        {   constexpr CR r = cnot_conj(1, L1);  // sigma_K = X
            float p2 = p * C[K][1];
            if constexpr (r.t != 0) p2 *= B[K + 1][r.t];
            s += chain<SM, K - 1, r.c, L0, F ^ r.flip>(B, C, p2); }
        {   constexpr CR r = cnot_conj(2, L1);  // sigma_K = Z
            float p2 = p * C[K][2];
            if constexpr (r.t != 0) p2 *= B[K + 1][r.t];
            s += chain<SM, K - 1, r.c, L0, F ^ r.flip>(B, C, p2); }
        {   constexpr CR r = cnot_conj(3, L1);  // sigma_K = Y
            float p2 = p * C[K][3];
            if constexpr (r.t != 0) p2 *= B[K + 1][r.t];
            s += chain<SM, K - 1, r.c, L0, F ^ r.flip>(B, C, p2); }
        return s;
    } else {
        constexpr CR r = cnot_conj(0, L1);      // sigma_K = I (pass-through)
        float p2 = p;
        if constexpr (r.t != 0) p2 *= B[K + 1][r.t];
        return chain<SM, K - 1, r.c, L0, F ^ r.flip>(B, C, p2);
    }
}

// Top: branch sigma_0 / sigma_9, apply H9=(9,0) first, then descend chain.
template<int SM, int S0, int S9>
__device__ __forceinline__ float top2(const float (&B)[NQ][4], const float (&C)[NQ][4]) {
    constexpr CR r = cnot_conj(S9, S0);         // H9: c=9, t=0
    float p = 1.f;
    if constexpr (S0 != 0) p *= C[0][S0];
    if constexpr (S9 != 0) p *= C[9][S9];
    return chain<SM, 8, r.c, r.t, r.flip>(B, C, p);
}
template<int SM, int S0>
__device__ __forceinline__ float sum9(const float (&B)[NQ][4], const float (&C)[NQ][4]) {
    if constexpr ((SM >> 9) & 1)
        return top2<SM, S0, 1>(B, C) + top2<SM, S0, 2>(B, C) + top2<SM, S0, 3>(B, C);
    else
        return top2<SM, S0, 0>(B, C);
}
template<int SM>
__device__ __forceinline__ float obs_eval(const float (&B)[NQ][4], const float (&C)[NQ][4]) {
    if constexpr (SM & 1)
        return sum9<SM, 1>(B, C) + sum9<SM, 2>(B, C) + sum9<SM, 3>(B, C);
    else
        return sum9<SM, 0>(B, C);
}

// ----------------------------------------------------------------------------
// ws layout (floats):
//  [w*6+0..2] = col0 of R0_w (coeff of sin x)   [w*6+3..5] = col2 (coeff of cos x)
//  [120+w] = cx, [130+w] = cz, [140+w] = cy   of M_w
// ----------------------------------------------------------------------------
__global__ void precompute(const float* __restrict__ weights, float* __restrict__ ws) {
    int w = threadIdx.x;
    if (w >= NQ) return;
    float phi0 = weights[w * 3 + 0], th0 = weights[w * 3 + 1], om0 = weights[w * 3 + 2];
    float phi1 = weights[(NQ + w) * 3 + 0], th1 = weights[(NQ + w) * 3 + 1];
    float cp, sp_, co, so, ct, st;
    sincosf(phi0, &sp_, &cp);
    sincosf(th0,  &st,  &ct);
    sincosf(om0,  &so,  &co);
    ws[w * 6 + 0] = co * ct * cp - so * sp_;   // Rz(om)Ry(th)Rz(phi) ex
    ws[w * 6 + 1] = so * ct * cp + co * sp_;
    ws[w * 6 + 2] = -st * cp;
    ws[w * 6 + 3] = co * st;                    // Rz(om)Ry(th) ez
    ws[w * 6 + 4] = so * st;
    ws[w * 6 + 5] = ct;
    float c1p, s1p, c1t, s1t;
    sincosf(phi1, &s1p, &c1p);
    sincosf(th1,  &s1t, &c1t);
    ws[120 + w] = -s1t * c1p;   // X coeff
    ws[130 + w] =  c1t;         // Z coeff
    ws[140 + w] =  s1t * s1p;   // Y coeff
}

__global__ __launch_bounds__(64) void qnn_kernel(
    const float* __restrict__ x, const float* __restrict__ ws,
    const float* __restrict__ w1, const float* __restrict__ b1,
    const float* __restrict__ w2, const float* __restrict__ b2,
    float* __restrict__ out)
{
    const int s = blockIdx.x * 64 + threadIdx.x;   // one sample per thread

    // per-wire Bloch vectors of (Rot0 RY(x))|0>:  B = sin(x)*col0 + cos(x)*col2
    float B[NQ][4];
    float C[NQ][4];
    const float2* xp = (const float2*)(x + s * NQ);  // 8B-aligned (40B stride)
    #pragma unroll
    for (int h = 0; h < 5; ++h) {
        float2 xv = xp[h];
        #pragma unroll
        for (int g = 0; g < 2; ++g) {
            int w = 2 * h + g;
            float sx, cx;
            sincosf(g ? xv.y : xv.x, &sx, &cx);
            const float* q = ws + w * 6;
            B[w][0] = 1.f;
            B[w][1] = fmaf(sx, q[0], cx * q[3]);   // <X>
            B[w][3] = fmaf(sx, q[1], cx * q[4]);   // <Y>
            B[w][2] = fmaf(sx, q[2], cx * q[5]);   // <Z>
            C[w][0] = 1.f;
            C[w][1] = ws[120 + w];
            C[w][2] = ws[130 + w];
            C[w][3] = ws[140 + w];
        }
    }

    float z[NQ];
    z[0] = obs_eval<0x154>(B, C);   // S_0 = {2,4,6,8}
    z[1] = obs_eval<0x2A8>(B, C);   // S_1 = {3,5,7,9}
    z[2] = obs_eval<0x005>(B, C);   // S_2 = {0,2}
    z[3] = obs_eval<0x00A>(B, C);   // S_3 = {1,3}
    z[4] = obs_eval<0x015>(B, C);   // S_4 = {0,2,4}
    z[5] = obs_eval<0x02A>(B, C);   // S_5 = {1,3,5}
    z[6] = obs_eval<0x055>(B, C);   // S_6 = {0,2,4,6}
    z[7] = obs_eval<0x0AA>(B, C);   // S_7 = {1,3,5,7}
    z[8] = obs_eval<0x155>(B, C);   // S_8 = {0,2,4,6,8}
    z[9] = obs_eval<0x2AA>(B, C);   // S_9 = {1,3,5,7,9}

    // MLP 10 -> 8 (relu) -> 1 (sigmoid); weights are uniform -> scalar loads
    float acc2 = b2[0];
    #pragma unroll
    for (int j = 0; j < 8; ++j) {
        float h = b1[j];
        #pragma unroll
        for (int w = 0; w < NQ; ++w)
            h = fmaf(z[w], w1[j * NQ + w], h);
        h = fmaxf(h, 0.f);
        acc2 = fmaf(h, w2[j], acc2);
    }
    out[s] = 1.f / (1.f + expf(-acc2));
}

extern "C" void kernel_launch(void* const* d_in, const int* in_sizes, int n_in,
                              void* d_out, int out_size, void* d_ws, size_t ws_size,
                              hipStream_t stream) {
    const float* x       = (const float*)d_in[0];
    const float* weights = (const float*)d_in[1];
    const float* w1      = (const float*)d_in[2];
    const float* b1      = (const float*)d_in[3];
    const float* w2      = (const float*)d_in[4];
    const float* b2      = (const float*)d_in[5];
    float* out = (float*)d_out;
    float* ws  = (float*)d_ws;   // 150 floats

    precompute<<<1, 64, 0, stream>>>(weights, ws);
    qnn_kernel<<<BATCH / 64, 64, 0, stream>>>(x, ws, w1, b1, w2, b2, out);
}

// Round 4
// 67.839 us; speedup vs baseline: 1.6677x; 1.0960x over previous
//
#include <hip/hip_runtime.h>
#include <math.h>

#define NQ 10
#define BATCH 4096

// ============================================================================
// Heisenberg-picture evaluation (verified bit-exact in R3). Per sample:
//   <Z_w> = <prod| Ring0^+ [ (x)_{b in S_w} M_b ] Ring0 |prod>
//   |prod> = (x)_w (Rot0_w RY(x_w))|0>   (per-wire Bloch vector, sample-dep)
//   M_b   = Rot1_b^+ Z Rot1_b = cz Z + cx X + cy Y (batch-uniform)
//   S_w   = ring-1-conjugated Z-string masks (compile-time)
// Ring-0 conjugation via compile-time template recursion; symplectic sign.
// Labels: I=0, X=1, Z=2, Y=3 (bit0 = x-part, bit1 = z-part)
// R4: 4 waves/block split the 10 observables (leafs 252/252/189/189);
//     uniform params computed in-block to LDS; no second kernel, no ws use.
// ============================================================================

struct CR { int c, t, flip; };
__host__ __device__ constexpr CR cnot_conj(int lc, int lt) {
    const int xc = lc & 1, zc = (lc >> 1) & 1;
    const int xt = lt & 1, zt = (lt >> 1) & 1;
    const int flip = xc & zt & ((xt ^ zc) ^ 1);
    const int nxt = xt ^ xc;
    const int nzc = zc ^ zt;
    return { (nzc << 1) | xc, (zt << 1) | nxt, flip };
}

template<int SM, int K, int L1, int L0, int F>
__device__ __forceinline__ float chain(const float (&B)[NQ][4], const float (&C)[NQ][4], float p) {
    if constexpr (K == 0) {
        constexpr CR r = cnot_conj(L0, L1);     // H0: c=0, t=1
        float v = p;
        if constexpr (r.t != 0) v *= B[1][r.t];
        if constexpr (r.c != 0) v *= B[0][r.c];
        if constexpr (F ^ r.flip) return -v; else return v;
    } else if constexpr ((SM >> K) & 1) {
        float s = 0.f;
        {   constexpr CR r = cnot_conj(1, L1);  // sigma_K = X
            float p2 = p * C[K][1];
            if constexpr (r.t != 0) p2 *= B[K + 1][r.t];
            s += chain<SM, K - 1, r.c, L0, F ^ r.flip>(B, C, p2); }
        {   constexpr CR r = cnot_conj(2, L1);  // sigma_K = Z
            float p2 = p * C[K][2];
            if constexpr (r.t != 0) p2 *= B[K + 1][r.t];
            s += chain<SM, K - 1, r.c, L0, F ^ r.flip>(B, C, p2); }
        {   constexpr CR r = cnot_conj(3, L1);  // sigma_K = Y
            float p2 = p * C[K][3];
            if constexpr (r.t != 0) p2 *= B[K + 1][r.t];
            s += chain<SM, K - 1, r.c, L0, F ^ r.flip>(B, C, p2); }
        return s;
    } else {
        constexpr CR r = cnot_conj(0, L1);      // sigma_K = I
        float p2 = p;
        if constexpr (r.t != 0) p2 *= B[K + 1][r.t];
        return chain<SM, K - 1, r.c, L0, F ^ r.flip>(B, C, p2);
    }
}

template<int SM, int S0, int S9>
__device__ __forceinline__ float top2(const float (&B)[NQ][4], const float (&C)[NQ][4]) {
    constexpr CR r = cnot_conj(S9, S0);         // H9: c=9, t=0
    float p = 1.f;
    if constexpr (S0 != 0) p *= C[0][S0];
    if constexpr (S9 != 0) p *= C[9][S9];
    return chain<SM, 8, r.c, r.t, r.flip>(B, C, p);
}
template<int SM, int S0>
__device__ __forceinline__ float sum9(const float (&B)[NQ][4], const float (&C)[NQ][4]) {
    if constexpr ((SM >> 9) & 1)
        return top2<SM, S0, 1>(B, C) + top2<SM, S0, 2>(B, C) + top2<SM, S0, 3>(B, C);
    else
        return top2<SM, S0, 0>(B, C);
}
template<int SM>
__device__ __forceinline__ float obs_eval(const float (&B)[NQ][4], const float (&C)[NQ][4]) {
    if constexpr (SM & 1)
        return sum9<SM, 1>(B, C) + sum9<SM, 2>(B, C) + sum9<SM, 3>(B, C);
    else
        return sum9<SM, 0>(B, C);
}

__global__ __launch_bounds__(256) void qnn_kernel(
    const float* __restrict__ x, const float* __restrict__ weights,
    const float* __restrict__ w1, const float* __restrict__ b1,
    const float* __restrict__ w2, const float* __restrict__ b2,
    float* __restrict__ out)
{
    __shared__ float U[60];          // per wire: R0 col0 (x3), R0 col2 (x3)
    __shared__ float CCs[40];        // per wire: {-, cx, cz, cy}
    __shared__ float zb[64 * 11];    // z[sample][wire], stride 11 (bank-safe)

    const int t = threadIdx.x;

    // ---- batch-uniform precompute (lanes 0..9 of wave 0) ----
    if (t < NQ) {
        float phi0 = weights[t * 3 + 0], th0 = weights[t * 3 + 1], om0 = weights[t * 3 + 2];
        float phi1 = weights[(NQ + t) * 3 + 0], th1 = weights[(NQ + t) * 3 + 1];
        float cp, sp_, co, so, ct, st;
        sincosf(phi0, &sp_, &cp);
        sincosf(th0,  &st,  &ct);
        sincosf(om0,  &so,  &co);
        U[t * 6 + 0] = co * ct * cp - so * sp_;   // Rz(om)Ry(th)Rz(phi) ex
        U[t * 6 + 1] = so * ct * cp + co * sp_;
        U[t * 6 + 2] = -st * cp;
        U[t * 6 + 3] = co * st;                    // Rz(om)Ry(th) ez
        U[t * 6 + 4] = so * st;
        U[t * 6 + 5] = ct;
        float c1p, s1p, c1t, s1t;
        sincosf(phi1, &s1p, &c1p);
        sincosf(th1,  &s1t, &c1t);
        CCs[t * 4 + 1] = -s1t * c1p;   // X coeff
        CCs[t * 4 + 2] =  c1t;         // Z coeff
        CCs[t * 4 + 3] =  s1t * s1p;   // Y coeff
    }
    __syncthreads();

    const int g    = t >> 6;                    // wave id = observable group
    const int lane = t & 63;
    const int sample = blockIdx.x * 64 + lane;

    // ---- per-wire Bloch vectors: B = sin(x)*col0 + cos(x)*col2 ----
    float B[NQ][4];
    float C[NQ][4];
    const float2* xp = (const float2*)(x + sample * NQ);
    #pragma unroll
    for (int h = 0; h < 5; ++h) {
        float2 xv = xp[h];
        #pragma unroll
        for (int q2 = 0; q2 < 2; ++q2) {
            int w = 2 * h + q2;
            float sx, cx;
            __sincosf(q2 ? xv.y : xv.x, &sx, &cx);
            B[w][0] = 1.f;
            B[w][1] = fmaf(sx, U[w * 6 + 0], cx * U[w * 6 + 3]);   // <X>
            B[w][3] = fmaf(sx, U[w * 6 + 1], cx * U[w * 6 + 4]);   // <Y>
            B[w][2] = fmaf(sx, U[w * 6 + 2], cx * U[w * 6 + 5]);   // <Z>
            C[w][0] = 1.f;
            C[w][1] = CCs[w * 4 + 1];
            C[w][2] = CCs[w * 4 + 2];
            C[w][3] = CCs[w * 4 + 3];
        }
    }

    // ---- tree evaluation, one observable group per wave (uniform branch) ----
    float* zrow = zb + lane * 11;
    if (g == 0) {
        zrow[8] = obs_eval<0x155>(B, C);   // S_8={0,2,4,6,8}  243 leaves
        zrow[2] = obs_eval<0x005>(B, C);   // S_2={0,2}          9
    } else if (g == 1) {
        zrow[9] = obs_eval<0x2AA>(B, C);   // S_9={1,3,5,7,9}  243
        zrow[3] = obs_eval<0x00A>(B, C);   // S_3={1,3}          9
    } else if (g == 2) {
        zrow[0] = obs_eval<0x154>(B, C);   // S_0={2,4,6,8}     81
        zrow[6] = obs_eval<0x055>(B, C);   // S_6={0,2,4,6}     81
        zrow[4] = obs_eval<0x015>(B, C);   // S_4={0,2,4}       27
    } else {
        zrow[1] = obs_eval<0x2A8>(B, C);   // S_1={3,5,7,9}     81
        zrow[7] = obs_eval<0x0AA>(B, C);   // S_7={1,3,5,7}     81
        zrow[5] = obs_eval<0x02A>(B, C);   // S_5={1,3,5}       27
    }
    __syncthreads();

    // ---- MLP 10 -> 8 (relu) -> 1 (sigmoid): wave 0, one sample per lane ----
    if (g == 0) {
        float z[NQ];
        #pragma unroll
        for (int w = 0; w < NQ; ++w) z[w] = zb[lane * 11 + w];
        float acc2 = b2[0];
        #pragma unroll
        for (int j = 0; j < 8; ++j) {
            float h = b1[j];
            #pragma unroll
            for (int w = 0; w < NQ; ++w)
                h = fmaf(z[w], w1[j * NQ + w], h);
            h = fmaxf(h, 0.f);
            acc2 = fmaf(h, w2[j], acc2);
        }
        out[sample] = 1.f / (1.f + __expf(-acc2));
    }
}

extern "C" void kernel_launch(void* const* d_in, const int* in_sizes, int n_in,
                              void* d_out, int out_size, void* d_ws, size_t ws_size,
                              hipStream_t stream) {
    const float* x       = (const float*)d_in[0];
    const float* weights = (const float*)d_in[1];
    const float* w1      = (const float*)d_in[2];
    const float* b1      = (const float*)d_in[3];
    const float* w2      = (const float*)d_in[4];
    const float* b2      = (const float*)d_in[5];
    float* out = (float*)d_out;

    qnn_kernel<<<BATCH / 64, 256, 0, stream>>>(x, weights, w1, b1, w2, b2, out);
}